// Round 7
// baseline (440.440 us; speedup 1.0000x reference)
//
#include <hip/hip_runtime.h>

// Problem constants (fixed by the reference)
#define Bn 2
#define Nn 256
#define Mn 512
#define Cn 256
#define Hn 8
#define MT 64             // m-tile size in fused kernel
#define SCALE_ 0.17677669529663687f   // Dh^-0.5, Dh=32
#define INV2PI 0.15915494309189535f

typedef short bf16x8 __attribute__((ext_vector_type(8)));
typedef short bf16x4 __attribute__((ext_vector_type(4)));
typedef float f32x4 __attribute__((ext_vector_type(4)));

static __device__ __forceinline__ float b2f(short s) {
    unsigned u = ((unsigned)(unsigned short)s) << 16;
    return __builtin_bit_cast(float, u);
}
static __device__ __forceinline__ short f2b(float f) {   // RNE f32->bf16
    unsigned u = __builtin_bit_cast(unsigned, f);
    u += 0x7fffu + ((u >> 16) & 1u);
    return (short)(u >> 16);
}

// ---- prep: one kernel for W1/W2 convert + q'/k'/v' projections ----
// bid 0..255: convert. 256..511: q' (8rx64c). 512..767: k' (32rx32c). 768..1023: v'.
__global__ __launch_bounds__(256) void prep(
        const float* __restrict__ query, const float* __restrict__ key,
        const float* __restrict__ Wq, const float* __restrict__ bq,
        const float* __restrict__ Wk, const float* __restrict__ Wv,
        const float* __restrict__ bv, const float* __restrict__ W1,
        const float* __restrict__ W2, short* __restrict__ W1b,
        short* __restrict__ W2b, float* __restrict__ qp,
        short* __restrict__ kTb, short* __restrict__ vTb) {
    __shared__ float arow[32][Cn];
    const int bid = blockIdx.x;
    const int t = threadIdx.x;
    if (bid < 256) {                       // convert W1/W2 to bf16
        const int i = bid * 256 + t;
        W1b[i] = f2b(W1[i]);
        W2b[i] = f2b(W2[i]);
        return;
    }
    if (bid < 512) {                       // q': 8 rows x 64 cols
        const int id = bid - 256;
        const int r0 = (id >> 2) * 8, c0 = (id & 3) * 64;
        #pragma unroll
        for (int i = 0; i < 8; ++i)
            if ((t >> 5) == i >> 2)        // 8 warps? simpler: strided fill
                ;
        // stage 8 rows (each thread fills col t of 8 rows)
        #pragma unroll
        for (int i = 0; i < 8; ++i) arow[i][t] = query[(size_t)(r0 + i) * Cn + t];
        __syncthreads();
        const int col = c0 + (t & 63);
        const int rs = t >> 6;             // 4 slots x 2 rows
        float a0 = 0.f, a1 = 0.f;
        const float* wr = Wq + (size_t)col * Cn;
        for (int k = 0; k < Cn; k += 4) {
            const float4 wv = *(const float4*)(wr + k);
            const int r = rs * 2;
            a0 += arow[r][k] * wv.x + arow[r][k+1] * wv.y
                + arow[r][k+2] * wv.z + arow[r][k+3] * wv.w;
            a1 += arow[r+1][k] * wv.x + arow[r+1][k+1] * wv.y
                + arow[r+1][k+2] * wv.z + arow[r+1][k+3] * wv.w;
        }
        const float bvv = bq[col];
        qp[(size_t)(r0 + rs * 2) * Cn + col] = a0 + bvv;
        qp[(size_t)(r0 + rs * 2 + 1) * Cn + col] = a1 + bvv;
        return;
    }
    // k'/v': 32 rows x 32 cols, transposed bf16 out
    const int isv = bid >= 768;
    const int id = bid - (isv ? 768 : 512);
    const int r0 = (id >> 3) * 32, c0 = (id & 7) * 32;
    const float* W = isv ? Wv : Wk;
    short* outb = isv ? vTb : kTb;
    #pragma unroll
    for (int i = 0; i < 32; ++i) arow[i][t] = key[(size_t)(r0 + i) * Cn + t];
    __syncthreads();
    const int col = c0 + (t & 31);
    const int rs = t >> 5;                 // 8 slots x 4 rows
    float a4[4] = {0.f, 0.f, 0.f, 0.f};
    const float* wr = W + (size_t)col * Cn;
    for (int k = 0; k < Cn; k += 4) {
        const float4 wv = *(const float4*)(wr + k);
        #pragma unroll
        for (int i = 0; i < 4; ++i) {
            const int r = rs * 4 + i;
            a4[i] += arow[r][k] * wv.x + arow[r][k+1] * wv.y
                   + arow[r][k+2] * wv.z + arow[r][k+3] * wv.w;
        }
    }
    const float bvv = isv ? bv[col] : 0.f;
    const int bk = r0 >> 9, mloc = (r0 & 511) + rs * 4;
    bf16x4 p;
    #pragma unroll
    for (int i = 0; i < 4; ++i) p[i] = f2b(a4[i] + bvv);
    *(bf16x4*)(outb + (size_t)(bk * Cn + col) * Mn + mloc) = p;
}

// ---- fused attention: time-shared 64-reg W buffer, K/V direct from L2 ----
// 512 threads = 8 waves; wave w owns output-channel slice [w*32, w*32+32) == head w.
// ~40 KB LDS + <=128 VGPR -> 2 blocks/CU, 4 waves/SIMD (phase overlap across blocks).
__global__ __launch_bounds__(512, 4) void fused_attn(
        const float* __restrict__ qp, const short* __restrict__ kTb,
        const short* __restrict__ vTb, const float* __restrict__ qpos,
        const short* __restrict__ W1b, const short* __restrict__ W2b,
        const float* __restrict__ b1, const float* __restrict__ b2,
        const float* __restrict__ freqs, float* __restrict__ xout) {
    __shared__ __align__(16) char embS[MT * 512];   // 32 KB emb/S, XOR-swizzled
    __shared__ float tposS[Mn];                     // 2 KB qpos row
    __shared__ float fbuf[128];                     // freqs / 2pi
    __shared__ float scb2[Hn * MT];                 // 2 KB scores -> weights
    __shared__ float pacc[512];                     // 2 KB
    __shared__ float corrS[Hn], lS[Hn];

    const int t = threadIdx.x;
    const int lane = t & 63;
    const int w = t >> 6;                 // wave id = head id = col-slice id
    const int lr = lane & 15, lg = lane >> 4;

    // XCD-chunked bijective swizzle: 512 blocks = 8 XCDs x 64 contiguous
    const int qrow = ((blockIdx.x & 7) << 6) | (blockIdx.x >> 3);
    const int b = qrow >> 8;              // batch

    const int cA = w * 32 + lr, cB = cA + 16;
    // W fragment bases (per-lane): frag kk at +kk*32 shorts
    const short* w1p0 = W1b + (size_t)cA * Cn + lg * 8;
    const short* w1p1 = W1b + (size_t)cB * Cn + lg * 8;
    const short* w2p0 = W2b + (size_t)cA * Cn + lg * 8;
    const short* w2p1 = W2b + (size_t)cB * Cn + lg * 8;

    // time-shared W fragment buffer (64 VGPRs): holds W1 for GEMM1, W2 for GEMM2
    bf16x8 wreg[16];
    #pragma unroll
    for (int kk = 0; kk < 8; ++kk) {
        wreg[kk] = *(const bf16x8*)(w1p0 + kk * 32);
        wreg[8 + kk] = *(const bf16x8*)(w1p1 + kk * 32);
    }

    const float b1v0 = b1[cA], b1v1 = b1[cB];
    const float b2v0 = b2[cA], b2v1 = b2[cB];
    const float q0 = qp[(size_t)qrow * Cn + cA];
    const float q1 = qp[(size_t)qrow * Cn + cB];
    tposS[t] = qpos[(size_t)qrow * Mn + t];
    if (t < 128) fbuf[t] = freqs[t] * INV2PI;
    const short* krow0 = kTb + (size_t)(b * Cn + cA) * Mn;
    const short* krow1 = kTb + (size_t)(b * Cn + cB) * Mn;
    float m_run = -1e30f, l_run = 0.f;
    float xacc = 0.f;                     // t<256: output channel t
    const f32x4 vzero = {0.f, 0.f, 0.f, 0.f};
    __syncthreads();

    for (int m0 = 0; m0 < Mn; m0 += MT) {
        // phase 1: embeddings -> embS. thread: m = t>>3, freq group fg = t&7 (16 f's)
        // v_sin/v_cos take revolutions; args < 0.16 rev -> no range reduction.
        {
            const int m = t >> 3, fg = t & 7;
            const float tv = tposS[m0 + m];
            bf16x8 pc[2], ps[2];
            #pragma unroll
            for (int j = 0; j < 16; ++j) {
                const float xr = tv * fbuf[fg * 16 + j];
                pc[j >> 3][j & 7] = f2b(__builtin_amdgcn_cosf(xr));
                ps[j >> 3][j & 7] = f2b(__builtin_amdgcn_sinf(xr));
            }
            char* rowp = embS + m * 512;
            const int sw = (m & 7) << 4;
            *(bf16x8*)(rowp + ((fg * 32) ^ sw)) = pc[0];        // cos -> cols [0:128)
            *(bf16x8*)(rowp + ((fg * 32 + 16) ^ sw)) = pc[1];
            *(bf16x8*)(rowp + ((256 + fg * 32) ^ sw)) = ps[0];  // sin -> cols [128:256)
            *(bf16x8*)(rowp + ((256 + fg * 32 + 16) ^ sw)) = ps[1];
        }
        __syncthreads();                  // (A) emb visible

        // phase 2: GEMM1  hidden = emb @ W1^T  (B = wreg)
        f32x4 acc[4][2];
        #pragma unroll
        for (int pb = 0; pb < 4; ++pb) { acc[pb][0] = vzero; acc[pb][1] = vzero; }
        #pragma unroll
        for (int pb = 0; pb < 4; ++pb) {
            const int row = pb * 16 + lr;
            const int sw = (row & 7) << 4;
            const char* rowp = embS + row * 512;
            #pragma unroll
            for (int kk = 0; kk < 8; ++kk) {
                const bf16x8 a = *(const bf16x8*)(rowp + ((lg * 16 + kk * 64) ^ sw));
                acc[pb][0] = __builtin_amdgcn_mfma_f32_16x16x32_bf16(a, wreg[kk],     acc[pb][0], 0, 0, 0);
                acc[pb][1] = __builtin_amdgcn_mfma_f32_16x16x32_bf16(a, wreg[8 + kk], acc[pb][1], 0, 0, 0);
            }
        }
        // refill wreg with W2 (L2-resident; drain overlaps silu phase)
        #pragma unroll
        for (int kk = 0; kk < 8; ++kk) {
            wreg[kk] = *(const bf16x8*)(w2p0 + kk * 32);
            wreg[8 + kk] = *(const bf16x8*)(w2p1 + kk * 32);
        }
        __syncthreads();                  // (B) all emb reads done

        // store S = silu(hidden + b1) back into embS (swizzled)
        #pragma unroll
        for (int pb = 0; pb < 4; ++pb) {
            #pragma unroll
            for (int jb = 0; jb < 2; ++jb) {
                const float bv = jb ? b1v1 : b1v0;
                const int j = w * 32 + jb * 16 + lr;
                #pragma unroll
                for (int r = 0; r < 4; ++r) {
                    const int row = pb * 16 + lg * 4 + r;   // C/D: row = 4*(lane>>4)+reg
                    float hv = acc[pb][jb][r] + bv;
                    hv = hv / (1.f + __expf(-hv));
                    *(short*)(embS + row * 512 + ((j * 2) ^ ((row & 7) << 4))) = f2b(hv);
                }
            }
        }
        __syncthreads();                  // (C) S visible

        // phase 3: GEMM2  P = S @ W2^T  (P stays in registers; B = wreg)
        #pragma unroll
        for (int pb = 0; pb < 4; ++pb) { acc[pb][0] = vzero; acc[pb][1] = vzero; }
        #pragma unroll
        for (int pb = 0; pb < 4; ++pb) {
            const int row = pb * 16 + lr;
            const int sw = (row & 7) << 4;
            const char* rowp = embS + row * 512;
            #pragma unroll
            for (int kk = 0; kk < 8; ++kk) {
                const bf16x8 a = *(const bf16x8*)(rowp + ((lg * 16 + kk * 64) ^ sw));
                acc[pb][0] = __builtin_amdgcn_mfma_f32_16x16x32_bf16(a, wreg[kk],     acc[pb][0], 0, 0, 0);
                acc[pb][1] = __builtin_amdgcn_mfma_f32_16x16x32_bf16(a, wreg[8 + kk], acc[pb][1], 0, 0, 0);
            }
        }
        // refill wreg with W1 for next tile
        #pragma unroll
        for (int kk = 0; kk < 8; ++kk) {
            wreg[kk] = *(const bf16x8*)(w1p0 + kk * 32);
            wreg[8 + kk] = *(const bf16x8*)(w1p1 + kk * 32);
        }

        // phase 4: scores for head w from P-registers + K rows from L2
        #pragma unroll
        for (int pb = 0; pb < 4; ++pb) {
            const int mmb = pb * 16 + lg * 4;
            const bf16x4 k4a = *(const bf16x4*)(krow0 + m0 + mmb);
            const bf16x4 k4b = *(const bf16x4*)(krow1 + m0 + mmb);
            #pragma unroll
            for (int r = 0; r < 4; ++r) {
                float v = (acc[pb][0][r] + b2v0) * q0 * b2f(k4a[r])
                        + (acc[pb][1][r] + b2v1) * q1 * b2f(k4b[r]);
                v += __shfl_xor(v, 1);
                v += __shfl_xor(v, 2);
                v += __shfl_xor(v, 4);
                v += __shfl_xor(v, 8);
                if (lr == 0) scb2[w * MT + mmb + r] = v * SCALE_;
            }
        }

        // phase 5: wave-local online softmax for head w
        {
            const float s = scb2[w * MT + lane];
            float tmax = s;
            #pragma unroll
            for (int msk = 1; msk < 64; msk <<= 1) tmax = fmaxf(tmax, __shfl_xor(tmax, msk));
            const float mnew = fmaxf(m_run, tmax);
            const float corr = __expf(m_run - mnew);
            const float e = __expf(s - mnew);
            scb2[w * MT + lane] = e;
            float ss = e;
            #pragma unroll
            for (int msk = 1; msk < 64; msk <<= 1) ss += __shfl_xor(ss, msk);
            l_run = l_run * corr + ss;
            m_run = mnew;
            if (lane == 0) corrS[w] = corr;
        }
        __syncthreads();                  // (D) weights + corrS visible

        // phase 6: PV partials. thread: c = t&255, m-half = t>>8; V rows from L2
        {
            const int c = t & 255, half = t >> 8;
            const int h = c >> 5;
            const short* vrow = vTb + (size_t)(b * Cn + c) * Mn + m0 + half * 32;
            const float* wr2 = scb2 + h * MT + half * 32;
            float s = 0.f;
            #pragma unroll
            for (int i = 0; i < 4; ++i) {
                const bf16x8 v8 = *(const bf16x8*)(vrow + i * 8);
                const float4 wa = *(const float4*)(wr2 + i * 8);
                const float4 wb = *(const float4*)(wr2 + i * 8 + 4);
                s += wa.x * b2f(v8[0]) + wa.y * b2f(v8[1]) + wa.z * b2f(v8[2]) + wa.w * b2f(v8[3])
                   + wb.x * b2f(v8[4]) + wb.y * b2f(v8[5]) + wb.z * b2f(v8[6]) + wb.w * b2f(v8[7]);
            }
            pacc[t] = s;
        }
        __syncthreads();                  // (E) pacc visible
        if (t < 256) xacc = xacc * corrS[t >> 5] + pacc[t] + pacc[t + 256];
    }

    if (lane == 0) lS[w] = l_run;
    __syncthreads();
    if (t < 256) xout[(size_t)qrow * Cn + t] = xacc / lS[t >> 5];
}

// ---- out-projection: out = x @ Wo^T + bo + query  (8 rows x 64 cols/block) ----
__global__ __launch_bounds__(256) void linear_out(
        const float* __restrict__ A, const float* __restrict__ W,
        const float* __restrict__ bias, const float* __restrict__ res,
        float* __restrict__ out) {
    __shared__ float arow[8][Cn];
    const int r0 = blockIdx.x * 8;
    const int c0 = blockIdx.y * 64;
    const int t = threadIdx.x;
    #pragma unroll
    for (int i = 0; i < 8; ++i) arow[i][t] = A[(size_t)(r0 + i) * Cn + t];
    __syncthreads();
    const int col = c0 + (t & 63);
    const int rs = t >> 6;
    float a0 = 0.f, a1 = 0.f;
    const float* wr = W + (size_t)col * Cn;
    for (int k = 0; k < Cn; k += 4) {
        const float4 wv = *(const float4*)(wr + k);
        const int r = rs * 2;
        a0 += arow[r][k] * wv.x + arow[r][k+1] * wv.y
            + arow[r][k+2] * wv.z + arow[r][k+3] * wv.w;
        a1 += arow[r+1][k] * wv.x + arow[r+1][k+1] * wv.y
            + arow[r+1][k+2] * wv.z + arow[r+1][k+3] * wv.w;
    }
    const float bvv = bias[col];
    const int row0 = r0 + rs * 2;
    out[(size_t)row0 * Cn + col] = a0 + bvv + res[(size_t)row0 * Cn + col];
    out[(size_t)(row0 + 1) * Cn + col] = a1 + bvv + res[(size_t)(row0 + 1) * Cn + col];
}

extern "C" void kernel_launch(void* const* d_in, const int* in_sizes, int n_in,
                              void* d_out, int out_size, void* d_ws, size_t ws_size,
                              hipStream_t stream) {
    const float* query = (const float*)d_in[0];
    const float* key   = (const float*)d_in[1];
    const float* qpos  = (const float*)d_in[2];
    const float* Wq    = (const float*)d_in[3];
    const float* bq    = (const float*)d_in[4];
    const float* Wk    = (const float*)d_in[5];
    const float* Wv    = (const float*)d_in[6];
    const float* bv    = (const float*)d_in[7];
    const float* Wo    = (const float*)d_in[8];
    const float* bo    = (const float*)d_in[9];
    const float* W1    = (const float*)d_in[10];
    const float* b1    = (const float*)d_in[11];
    const float* W2    = (const float*)d_in[12];
    const float* b2    = (const float*)d_in[13];
    const float* freqs = (const float*)d_in[14];
    float* out = (float*)d_out;

    char* ws = (char*)d_ws;
    float* qp  = (float*)(ws);                 // 512 KB  (B*N*C f32)
    short* kTb = (short*)(ws + 524288);        // 512 KB  (B*C*M bf16, transposed)
    short* vTb = (short*)(ws + 1048576);       // 512 KB
    float* xo  = (float*)(ws + 1572864);       // 512 KB
    short* W1b = (short*)(ws + 2097152);       // 128 KB bf16
    short* W2b = (short*)(ws + 2228224);       // 128 KB bf16 (contiguous after W1b)

    prep<<<1024, 256, 0, stream>>>(query, key, Wq, bq, Wk, Wv, bv, W1, W2,
                                   W1b, W2b, qp, kTb, vTb);
    fused_attn<<<Bn * Nn, 512, 0, stream>>>(qp, kTb, vTb, qpos, W1b, W2b, b1, b2, freqs, xo);
    linear_out<<<dim3(64, 4), 256, 0, stream>>>(xo, Wo, bo, query, out);
}